// Round 3
// baseline (528.659 us; speedup 1.0000x reference)
//
#include <hip/hip_runtime.h>
#include <math.h>

#define BATCH 128
#define CIN 3
#define H 224
#define W 224
#define C1 16
#define HP 56
#define WP 56
#define C2 32
#define H2 28
#define W2 28

#define PITCH1 236   // 228 data cols + swizzle headroom (max idx 227+7=234)
#define PITCH2 61    // 58 data cols + odd pitch to spread banks across rows

// ---------------------------------------------------------------------------
// conv1 (s2,p1) + stats + 2x2 pool(max,min), all 16 channels per thread.
// Grid (14,128): 4 pooled rows per block. LDS x-tile swizzled (col+(col>>5))
// so the stride-4 patch reads land <=3 lanes/bank (was 8-way on b128).
// Output: interleaved float2 (max,min) of the raw conv 2x2 window.
// ---------------------------------------------------------------------------
__global__ __launch_bounds__(256, 3) void conv1_fused_k(
    const float* __restrict__ x, const float* __restrict__ w1,
    const float* __restrict__ b1,
    float2* __restrict__ mm,
    float* __restrict__ s_sum, float* __restrict__ s_sq)
{
    __shared__ float xs[CIN * 17 * PITCH1];
    __shared__ float rsum[4][16];
    __shared__ float rsq[4][16];
    const int tid = threadIdx.x;
    const int ty  = blockIdx.x;           // 0..13
    const int n   = blockIdx.y;
    const int r0  = 16 * ty - 1;

    // ---- stage: row-structured, no div/mod, uniform row bounds ----
    if (tid < 228) {
        const int gc = tid - 1;
        const bool cok = (gc >= 0) && (gc < W);
        const int dst0 = tid + (tid >> 5);
#pragma unroll
        for (int ci = 0; ci < CIN; ++ci) {
            const float* img = x + (n * CIN + ci) * (H * W);
#pragma unroll 4
            for (int l = 0; l < 17; ++l) {
                const int g = r0 + l;                 // uniform per iter
                float v = 0.0f;
                if (g >= 0 && g < H && cok) v = img[g * W + gc];
                xs[(ci * 17 + l) * PITCH1 + dst0] = v;
            }
        }
    }
    __syncthreads();

    const bool active = tid < 224;
    const int t = active ? tid : 0;
    const int pr  = t / 56;               // local pooled row 0..3
    const int owp = t % 56;               // pooled col

    float acc[16][4];
#pragma unroll
    for (int j = 0; j < 16; ++j) {
        const float bb = b1[j];
        acc[j][0] = bb; acc[j][1] = bb; acc[j][2] = bb; acc[j][3] = bb;
    }

#pragma unroll
    for (int ci = 0; ci < CIN; ++ci) {
        float p[5][5];
#pragma unroll
        for (int r = 0; r < 5; ++r) {
            const int rowb = (ci * 17 + 4 * pr + r) * PITCH1;
#pragma unroll
            for (int s = 0; s < 5; ++s) {
                const int c = 4 * owp + s;
                p[r][s] = xs[rowb + c + (c >> 5)];
            }
        }
#pragma unroll
        for (int j = 0; j < 16; ++j) {
            const float* wc = w1 + (j * CIN + ci) * 9;   // uniform -> s_load
#pragma unroll
            for (int kh = 0; kh < 3; ++kh) {
#pragma unroll
                for (int kw = 0; kw < 3; ++kw) {
                    const float wv = wc[kh * 3 + kw];
                    acc[j][0] += wv * p[kh][kw];
                    acc[j][1] += wv * p[kh][kw + 2];
                    acc[j][2] += wv * p[kh + 2][kw];
                    acc[j][3] += wv * p[kh + 2][kw + 2];
                }
            }
        }
    }

#pragma unroll
    for (int j = 0; j < 16; ++j) {
        const float a0 = acc[j][0], a1 = acc[j][1], a2 = acc[j][2], a3 = acc[j][3];
        if (active) {
            const int o = (n * C1 + j) * (HP * WP) + (4 * ty + pr) * WP + owp;
            mm[o] = make_float2(fmaxf(fmaxf(a0, a1), fmaxf(a2, a3)),
                                fminf(fminf(a0, a1), fminf(a2, a3)));
        }
        float s = active ? (a0 + a1 + a2 + a3) : 0.0f;
        float q = active ? (a0 * a0 + a1 * a1 + a2 * a2 + a3 * a3) : 0.0f;
#pragma unroll
        for (int off = 32; off > 0; off >>= 1) {
            s += __shfl_xor(s, off);
            q += __shfl_xor(q, off);
        }
        if ((tid & 63) == 0) { rsum[tid >> 6][j] = s; rsq[tid >> 6][j] = q; }
    }
    __syncthreads();
    if (tid < 16) {
        atomicAdd(&s_sum[tid], rsum[0][tid] + rsum[1][tid] + rsum[2][tid] + rsum[3][tid]);
    } else if (tid < 32) {
        const int c = tid - 16;
        atomicAdd(&s_sq[c], rsq[0][c] + rsq[1][c] + rsq[2][c] + rsq[3][c]);
    }
}

__global__ void finalize_bn_k(const float* __restrict__ s_sum,
                              const float* __restrict__ s_sq,
                              const float* __restrict__ g,
                              const float* __restrict__ beta,
                              float* __restrict__ sc, int C, float invcount)
{
    int c = threadIdx.x;
    if (c < C) {
        float mean = s_sum[c] * invcount;
        float var  = s_sq[c] * invcount - mean * mean;
        float scale = g[c] * rsqrtf(var + 1e-5f);
        sc[c]     = scale;
        sc[C + c] = beta[c] - mean * scale;
    }
}

// ---------------------------------------------------------------------------
// conv2 (s2,p1) + stats. Staging applies BN1 + relu + pool-select:
//   h1 = max(0, max(s*mx+t, s*mn+t)).
// Grid (7,128): 4 output rows per 128-thread block (112 active). LDS 35 KB
// -> 4 blocks/CU. Thread = one output position, all 32 channels.
// ---------------------------------------------------------------------------
__global__ __launch_bounds__(128) void conv2_fused_k(
    const float2* __restrict__ mm, const float* __restrict__ sc1,
    const float* __restrict__ w2, const float* __restrict__ b2,
    float* __restrict__ y2,
    float* __restrict__ s_sum, float* __restrict__ s_sq)
{
    __shared__ float hs[C1 * 9 * PITCH2];
    __shared__ float rsum[2][32];
    __shared__ float rsq[2][32];
    const int tid = threadIdx.x;
    const int t3  = blockIdx.x;            // 0..6
    const int n   = blockIdx.y;
    const int r0  = 8 * t3 - 1;

    // ---- stage: 2 rows of 58 per iteration (116 of 128 lanes) ----
    const int rsel = (tid >= 58) ? 1 : 0;
    const int col  = tid - rsel * 58;      // 0..57
    const bool sact = tid < 116;
    const int gc = col - 1;
    const bool cok = (gc >= 0) && (gc < WP);
#pragma unroll
    for (int ci = 0; ci < C1; ++ci) {
        const float s1 = sc1[ci], t1 = sc1[C1 + ci];
        const int base = (n * C1 + ci) * (HP * WP);
#pragma unroll
        for (int it = 0; it < 5; ++it) {
            const int l = 2 * it + rsel;   // 0..9 (9 invalid)
            const int g = r0 + l;
            const bool ok = sact && (l < 9) && (g >= 0) && (g < HP) && cok;
            float v = 0.0f;
            if (ok) {
                const float2 ab = mm[base + g * WP + gc];
                v = fmaxf(0.0f, fmaxf(s1 * ab.x + t1, s1 * ab.y + t1));
            }
            if (sact && (l < 9)) hs[(ci * 9 + l) * PITCH2 + col] = v;
        }
    }
    __syncthreads();

    const bool active = tid < 112;
    const int t = active ? tid : 0;
    const int ohl = t / 28, ow = t % 28;

    float acc[32];
#pragma unroll
    for (int c = 0; c < 32; ++c) acc[c] = b2[c];

#pragma unroll
    for (int ci = 0; ci < C1; ++ci) {
        float v[9];
#pragma unroll
        for (int kh = 0; kh < 3; ++kh)
#pragma unroll
            for (int kw = 0; kw < 3; ++kw)
                v[kh * 3 + kw] = hs[(ci * 9 + 2 * ohl + kh) * PITCH2 + 2 * ow + kw];
#pragma unroll
        for (int c = 0; c < 32; ++c) {
            const float* wc = w2 + (c * C1 + ci) * 9;    // uniform -> s_load
            float a = acc[c];
            a += wc[0] * v[0]; a += wc[1] * v[1]; a += wc[2] * v[2];
            a += wc[3] * v[3]; a += wc[4] * v[4]; a += wc[5] * v[5];
            a += wc[6] * v[6]; a += wc[7] * v[7]; a += wc[8] * v[8];
            acc[c] = a;
        }
    }

    const int oh = 4 * t3 + ohl;
#pragma unroll
    for (int c = 0; c < 32; ++c) {
        const float a = acc[c];
        if (active) y2[(n * C2 + c) * (H2 * W2) + oh * W2 + ow] = a;
        float s = active ? a : 0.0f;
        float q = active ? a * a : 0.0f;
#pragma unroll
        for (int off = 32; off > 0; off >>= 1) {
            s += __shfl_xor(s, off);
            q += __shfl_xor(q, off);
        }
        if ((tid & 63) == 0) { rsum[tid >> 6][c] = s; rsq[tid >> 6][c] = q; }
    }
    __syncthreads();
    if (tid < 32) {
        atomicAdd(&s_sum[tid], rsum[0][tid] + rsum[1][tid]);
    } else if (tid < 64) {
        const int c = tid - 32;
        atomicAdd(&s_sq[c], rsq[0][c] + rsq[1][c]);
    }
}

// ---------------------------------------------------------------------------
// head: one wave per (n, c): BN2+relu+avg over 784, dot with fcw, atomic
// into per-image logit. 4096 blocks -> 16 waves/CU.
// ---------------------------------------------------------------------------
__global__ __launch_bounds__(64) void head_k(
    const float* __restrict__ y2, const float* __restrict__ sc2,
    const float* __restrict__ fcw, float* __restrict__ logit)
{
    const int b = blockIdx.x;
    const int n = b >> 5, c = b & 31;
    const int lane = threadIdx.x;
    const float s = sc2[c], t = sc2[C2 + c];
    const float* yp = y2 + (size_t)b * (H2 * W2);
    float acc = 0.0f;
    for (int p = lane; p < H2 * W2; p += 64)
        acc += fmaxf(0.0f, s * yp[p] + t);
#pragma unroll
    for (int off = 32; off > 0; off >>= 1) acc += __shfl_xor(acc, off);
    if (lane == 0)
        atomicAdd(&logit[n], acc * (1.0f / (H2 * W2)) * fcw[c]);
}

__global__ void cos_k(const float* __restrict__ logit,
                      const float* __restrict__ fcb, float* __restrict__ out)
{
    const int n = threadIdx.x;   // 128
    const float pc = cosf(logit[n] + fcb[0]);
    out[2 * n]     = pc;
    out[2 * n + 1] = 1.0f - pc;
}

extern "C" void kernel_launch(void* const* d_in, const int* in_sizes, int n_in,
                              void* d_out, int out_size, void* d_ws, size_t ws_size,
                              hipStream_t stream) {
    const float* x   = (const float*)d_in[0];
    const float* w1  = (const float*)d_in[1];
    const float* b1  = (const float*)d_in[2];
    const float* g1  = (const float*)d_in[3];
    const float* be1 = (const float*)d_in[4];
    const float* w2  = (const float*)d_in[5];
    const float* b2  = (const float*)d_in[6];
    const float* g2  = (const float*)d_in[7];
    const float* be2 = (const float*)d_in[8];
    const float* fcw = (const float*)d_in[9];
    const float* fcb = (const float*)d_in[10];
    float* out = (float*)d_out;

    float* ws = (float*)d_ws;
    float2* mm = (float2*)ws;                              // 6,422,528 float2
    float* y2 = ws + (size_t)2 * BATCH * C1 * HP * WP;     // 3,211,264 floats
    float* stats = y2 + (size_t)BATCH * C2 * H2 * W2;
    float* s1sum = stats;          // 16
    float* s1sq  = stats + 16;     // 16
    float* s2sum = stats + 32;     // 32
    float* s2sq  = stats + 64;     // 32
    float* logit = stats + 96;     // 128
    float* sc1   = stats + 224;    // 32
    float* sc2   = stats + 256;    // 64

    hipMemsetAsync(stats, 0, 224 * sizeof(float), stream);

    conv1_fused_k<<<dim3(14, BATCH), 256, 0, stream>>>(x, w1, b1, mm, s1sum, s1sq);
    finalize_bn_k<<<1, 64, 0, stream>>>(s1sum, s1sq, g1, be1, sc1, C1,
                                        1.0f / (float)(BATCH * 112 * 112));
    conv2_fused_k<<<dim3(7, BATCH), 128, 0, stream>>>(mm, sc1, w2, b2, y2, s2sum, s2sq);
    finalize_bn_k<<<1, 64, 0, stream>>>(s2sum, s2sq, g2, be2, sc2, C2,
                                        1.0f / (float)(BATCH * H2 * W2));
    head_k<<<BATCH * C2, 64, 0, stream>>>(y2, sc2, fcw, logit);
    cos_k<<<1, BATCH, 0, stream>>>(logit, fcb, out);
}

// Round 4
// 273.147 us; speedup vs baseline: 1.9354x; 1.9354x over previous
//
#include <hip/hip_runtime.h>
#include <math.h>

#define BATCH 128
#define CIN 3
#define H 224
#define W 224
#define C1 16
#define HP 56
#define WP 56
#define C2 32
#define H2 28
#define W2 28

// ---------------------------------------------------------------------------
// conv1 core: one thread computes the 2x2 conv-output window (stride-2 conv,
// pad 1) feeding pooled cell (ph,pw), for 8 output channels c0..c0+7.
// Register patch per in-channel: rows ih=4ph-1+r (r=0..4), cols iw=4pw-1+s.
// Loads are UNCONDITIONAL: float4 at col 4pw (16B-aligned), scalar at col
// 4pw-1 (address clamped). Only r==0 (ph==0) and s==0 (pw==0) need value
// masks; r/s are compile-time so masks fold away for interior taps.
// ---------------------------------------------------------------------------
__device__ __forceinline__ void conv1_core(
    const float* __restrict__ x, const float* __restrict__ w1, int n,
    int ph, int pw, int c0, float acc[8][4])
{
    const int rbase = 4 * ph - 1;
    const int cbase = 4 * pw;
    const bool phok = ph > 0;
    const bool pwok = pw > 0;
#pragma unroll
    for (int ci = 0; ci < CIN; ++ci) {
        const float* img = x + (n * CIN + ci) * (H * W);
        float p[5][5];
#pragma unroll
        for (int r = 0; r < 5; ++r) {
            const int ih = max(rbase + r, 0);
            const float* rowp = img + ih * W;
            const float4 f4 = *(const float4*)(rowp + cbase);
            const float lf = rowp[max(cbase - 1, 0)];
            const bool rok = (r > 0) || phok;     // folds for r>0
            p[r][0] = (rok && pwok) ? lf : 0.0f;
            p[r][1] = rok ? f4.x : 0.0f;
            p[r][2] = rok ? f4.y : 0.0f;
            p[r][3] = rok ? f4.z : 0.0f;
            p[r][4] = rok ? f4.w : 0.0f;
        }
#pragma unroll
        for (int j = 0; j < 8; ++j) {
            const float* wc = w1 + ((c0 + j) * CIN + ci) * 9;  // uniform
#pragma unroll
            for (int kh = 0; kh < 3; ++kh) {
#pragma unroll
                for (int kw = 0; kw < 3; ++kw) {
                    const float wv = wc[kh * 3 + kw];
                    acc[j][0] += wv * p[kh][kw];
                    acc[j][1] += wv * p[kh][kw + 2];
                    acc[j][2] += wv * p[kh + 2][kw];
                    acc[j][3] += wv * p[kh + 2][kw + 2];
                }
            }
        }
    }
}

// Pass 1: stats only. Grid (1568, 2): 1568*256 = 128*3136 exactly.
__global__ __launch_bounds__(256) void conv1_stats_k(
    const float* __restrict__ x, const float* __restrict__ w1,
    const float* __restrict__ b1,
    float* __restrict__ s_sum, float* __restrict__ s_sq)
{
    __shared__ float red[4][8], redq[4][8];
    const int tid = threadIdx.x;
    const int t = blockIdx.x * 256 + tid;
    const int c0 = blockIdx.y * 8;
    const int n = t / 3136;
    const int p = t % 3136;
    const int ph = p / WP, pw = p % WP;

    float acc[8][4];
#pragma unroll
    for (int j = 0; j < 8; ++j) {
        const float bb = b1[c0 + j];
        acc[j][0] = bb; acc[j][1] = bb; acc[j][2] = bb; acc[j][3] = bb;
    }
    conv1_core(x, w1, n, ph, pw, c0, acc);

#pragma unroll
    for (int j = 0; j < 8; ++j) {
        float s = acc[j][0] + acc[j][1] + acc[j][2] + acc[j][3];
        float q = acc[j][0] * acc[j][0] + acc[j][1] * acc[j][1]
                + acc[j][2] * acc[j][2] + acc[j][3] * acc[j][3];
#pragma unroll
        for (int off = 32; off > 0; off >>= 1) {
            s += __shfl_xor(s, off);
            q += __shfl_xor(q, off);
        }
        if ((tid & 63) == 0) { red[tid >> 6][j] = s; redq[tid >> 6][j] = q; }
    }
    __syncthreads();
    if (tid < 8) {
        atomicAdd(&s_sum[c0 + tid],
                  red[0][tid] + red[1][tid] + red[2][tid] + red[3][tid]);
    } else if (tid < 16) {
        const int j = tid - 8;
        atomicAdd(&s_sq[c0 + j],
                  redq[0][j] + redq[1][j] + redq[2][j] + redq[3][j]);
    }
}

// Pass 2: recompute conv1, apply BN1+ReLU+2x2 maxpool, write h1.
// relu(bn(a)) pooled == relu(max(s*mx+t, s*mn+t)) (covers both signs of s).
__global__ __launch_bounds__(256) void conv1_apply_k(
    const float* __restrict__ x, const float* __restrict__ w1,
    const float* __restrict__ b1, const float* __restrict__ sc1,
    float* __restrict__ h1)
{
    const int tid = threadIdx.x;
    const int t = blockIdx.x * 256 + tid;
    const int c0 = blockIdx.y * 8;
    const int n = t / 3136;
    const int p = t % 3136;
    const int ph = p / WP, pw = p % WP;

    float acc[8][4];
#pragma unroll
    for (int j = 0; j < 8; ++j) {
        const float bb = b1[c0 + j];
        acc[j][0] = bb; acc[j][1] = bb; acc[j][2] = bb; acc[j][3] = bb;
    }
    conv1_core(x, w1, n, ph, pw, c0, acc);

#pragma unroll
    for (int j = 0; j < 8; ++j) {
        const float s = sc1[c0 + j], tt = sc1[C1 + c0 + j];
        const float mx = fmaxf(fmaxf(acc[j][0], acc[j][1]),
                               fmaxf(acc[j][2], acc[j][3]));
        const float mn = fminf(fminf(acc[j][0], acc[j][1]),
                               fminf(acc[j][2], acc[j][3]));
        h1[(n * C1 + c0 + j) * 3136 + p] =
            fmaxf(0.0f, fmaxf(s * mx + tt, s * mn + tt));
    }
}

__global__ void finalize_bn_k(const float* __restrict__ s_sum,
                              const float* __restrict__ s_sq,
                              const float* __restrict__ g,
                              const float* __restrict__ beta,
                              float* __restrict__ sc, int C, float invcount)
{
    int c = threadIdx.x;
    if (c < C) {
        float mean = s_sum[c] * invcount;
        float var  = s_sq[c] * invcount - mean * mean;
        float scale = g[c] * rsqrtf(var + 1e-5f);
        sc[c]     = scale;
        sc[C + c] = beta[c] - mean * scale;
    }
}

// ---------------------------------------------------------------------------
// conv2 (s2,p1) direct + stats. Thread = one output position x 8 channels.
// Grid (392, 4): 392*256 = 128*784 exactly. Reads h1 unconditionally:
// float2 at col 2*ow (8B-aligned) + scalar at 2*ow-1 (clamped+masked).
// ---------------------------------------------------------------------------
__global__ __launch_bounds__(256) void conv2_k(
    const float* __restrict__ h1, const float* __restrict__ w2,
    const float* __restrict__ b2, float* __restrict__ y2,
    float* __restrict__ s_sum, float* __restrict__ s_sq)
{
    __shared__ float red[4][8], redq[4][8];
    const int tid = threadIdx.x;
    const int t = blockIdx.x * 256 + tid;
    const int c0 = blockIdx.y * 8;
    const int n = t / 784;
    const int p = t % 784;
    const int oh = p / W2, ow = p % W2;
    const bool ohok = oh > 0;
    const bool owok = ow > 0;

    float acc[8];
#pragma unroll
    for (int c = 0; c < 8; ++c) acc[c] = b2[c0 + c];

#pragma unroll 4
    for (int ci = 0; ci < C1; ++ci) {
        const float* pl = h1 + (n * C1 + ci) * (HP * WP);
        float v[3][3];
#pragma unroll
        for (int kh = 0; kh < 3; ++kh) {
            const int ih = max(2 * oh - 1 + kh, 0);
            const float* rowp = pl + ih * WP;
            const float2 f2 = *(const float2*)(rowp + 2 * ow);
            const float lf = rowp[max(2 * ow - 1, 0)];
            const bool rok = (kh > 0) || ohok;    // folds for kh>0
            v[kh][0] = (rok && owok) ? lf : 0.0f;
            v[kh][1] = rok ? f2.x : 0.0f;
            v[kh][2] = rok ? f2.y : 0.0f;
        }
#pragma unroll
        for (int c = 0; c < 8; ++c) {
            const float* wc = w2 + ((c0 + c) * C1 + ci) * 9;   // uniform
            float a = acc[c];
            a += wc[0] * v[0][0]; a += wc[1] * v[0][1]; a += wc[2] * v[0][2];
            a += wc[3] * v[1][0]; a += wc[4] * v[1][1]; a += wc[5] * v[1][2];
            a += wc[6] * v[2][0]; a += wc[7] * v[2][1]; a += wc[8] * v[2][2];
            acc[c] = a;
        }
    }

#pragma unroll
    for (int c = 0; c < 8; ++c) {
        const float a = acc[c];
        y2[(n * C2 + c0 + c) * (H2 * W2) + p] = a;
        float s = a, q = a * a;
#pragma unroll
        for (int off = 32; off > 0; off >>= 1) {
            s += __shfl_xor(s, off);
            q += __shfl_xor(q, off);
        }
        if ((tid & 63) == 0) { red[tid >> 6][c] = s; redq[tid >> 6][c] = q; }
    }
    __syncthreads();
    if (tid < 8) {
        atomicAdd(&s_sum[c0 + tid],
                  red[0][tid] + red[1][tid] + red[2][tid] + red[3][tid]);
    } else if (tid < 16) {
        const int c = tid - 8;
        atomicAdd(&s_sq[c0 + c],
                  redq[0][c] + redq[1][c] + redq[2][c] + redq[3][c]);
    }
}

// ---------------------------------------------------------------------------
// head: one wave per (n,c): BN2+relu+avg over 784, dot with fcw, atomic
// into per-image logit.
// ---------------------------------------------------------------------------
__global__ __launch_bounds__(64) void head_k(
    const float* __restrict__ y2, const float* __restrict__ sc2,
    const float* __restrict__ fcw, float* __restrict__ logit)
{
    const int b = blockIdx.x;
    const int n = b >> 5, c = b & 31;
    const int lane = threadIdx.x;
    const float s = sc2[c], t = sc2[C2 + c];
    const float* yp = y2 + (size_t)b * (H2 * W2);
    float acc = 0.0f;
    for (int p = lane; p < H2 * W2; p += 64)
        acc += fmaxf(0.0f, s * yp[p] + t);
#pragma unroll
    for (int off = 32; off > 0; off >>= 1) acc += __shfl_xor(acc, off);
    if (lane == 0)
        atomicAdd(&logit[n], acc * (1.0f / (H2 * W2)) * fcw[c]);
}

__global__ void cos_k(const float* __restrict__ logit,
                      const float* __restrict__ fcb, float* __restrict__ out)
{
    const int n = threadIdx.x;   // 128
    const float pc = cosf(logit[n] + fcb[0]);
    out[2 * n]     = pc;
    out[2 * n + 1] = 1.0f - pc;
}

extern "C" void kernel_launch(void* const* d_in, const int* in_sizes, int n_in,
                              void* d_out, int out_size, void* d_ws, size_t ws_size,
                              hipStream_t stream) {
    const float* x   = (const float*)d_in[0];
    const float* w1  = (const float*)d_in[1];
    const float* b1  = (const float*)d_in[2];
    const float* g1  = (const float*)d_in[3];
    const float* be1 = (const float*)d_in[4];
    const float* w2  = (const float*)d_in[5];
    const float* b2  = (const float*)d_in[6];
    const float* g2  = (const float*)d_in[7];
    const float* be2 = (const float*)d_in[8];
    const float* fcw = (const float*)d_in[9];
    const float* fcb = (const float*)d_in[10];
    float* out = (float*)d_out;

    float* ws = (float*)d_ws;
    float* h1 = ws;                                        // 6,422,528 floats
    float* y2 = h1 + (size_t)BATCH * C1 * HP * WP;         // 3,211,264 floats
    float* stats = y2 + (size_t)BATCH * C2 * H2 * W2;
    float* s1sum = stats;          // 16
    float* s1sq  = stats + 16;     // 16
    float* s2sum = stats + 32;     // 32
    float* s2sq  = stats + 64;     // 32
    float* logit = stats + 96;     // 128
    float* sc1   = stats + 224;    // 32
    float* sc2   = stats + 256;    // 64
    // ws use ~38.6 MB (known-safe; R1 used 38.5)

    hipMemsetAsync(stats, 0, 224 * sizeof(float), stream);

    conv1_stats_k<<<dim3(1568, 2), 256, 0, stream>>>(x, w1, b1, s1sum, s1sq);
    finalize_bn_k<<<1, 64, 0, stream>>>(s1sum, s1sq, g1, be1, sc1, C1,
                                        1.0f / (float)(BATCH * 112 * 112));
    conv1_apply_k<<<dim3(1568, 2), 256, 0, stream>>>(x, w1, b1, sc1, h1);
    conv2_k<<<dim3(392, 4), 256, 0, stream>>>(h1, w2, b2, y2, s2sum, s2sq);
    finalize_bn_k<<<1, 64, 0, stream>>>(s2sum, s2sq, g2, be2, sc2, C2,
                                        1.0f / (float)(BATCH * H2 * W2));
    head_k<<<BATCH * C2, 64, 0, stream>>>(y2, sc2, fcw, logit);
    cos_k<<<1, BATCH, 0, stream>>>(logit, fcb, out);
}

// Round 5
// 240.412 us; speedup vs baseline: 2.1990x; 1.1362x over previous
//
#include <hip/hip_runtime.h>
#include <math.h>

#define BATCH 128
#define CIN 3
#define H 224
#define W 224
#define C1 16
#define HP 56
#define WP 56
#define C2 32
#define H2 28
#define W2 28

// ---------------------------------------------------------------------------
// conv1 (s2,p1) + stats + 2x2 pool(max,min), SINGLE PASS.
// Thread = 2 vertically-adjacent pooled cells (ph=2*phh, 2*phh+1) x 8 chans.
// Input rows 8*phh-1 .. 8*phh+7 (9 rows, cell A uses l=0..4, B uses l=4..8).
// Loads unconditional: float4 @ col 4*pw (16B-aligned) + clamped scalar at
// 4*pw-1; only l==0 (phh==0) and col0 (pw==0) need value masks (fold away
// for interior taps). Output: interleaved float2 (max,min) of raw conv 2x2
// window; BN applied later by conv2's staging.
// Grid (784, 2): 784*256 = 128*28*56 exactly.
// ---------------------------------------------------------------------------
__global__ __launch_bounds__(256) void conv1_fused_k(
    const float* __restrict__ x, const float* __restrict__ w1,
    const float* __restrict__ b1, float2* __restrict__ mm,
    float* __restrict__ s_sum, float* __restrict__ s_sq)
{
    __shared__ float red[4][8], redq[4][8];
    const int tid = threadIdx.x;
    const int t = blockIdx.x * 256 + tid;   // 0..200703
    const int c0 = blockIdx.y * 8;
    const int n = t / 1568;
    const int r = t % 1568;
    const int phh = r / 56;                 // 0..27
    const int pw  = r % 56;
    const int rbase = 8 * phh - 1;
    const int cbase = 4 * pw;
    const bool topok = phh > 0;
    const bool pwok  = pw > 0;

    float accA[8][4], accB[8][4];
#pragma unroll
    for (int j = 0; j < 8; ++j) {
        const float bb = b1[c0 + j];
#pragma unroll
        for (int q = 0; q < 4; ++q) { accA[j][q] = bb; accB[j][q] = bb; }
    }

#pragma unroll
    for (int ci = 0; ci < CIN; ++ci) {
        const float* img = x + (n * CIN + ci) * (H * W);
        float p[9][5];
#pragma unroll
        for (int l = 0; l < 9; ++l) {
            const int ih = max(rbase + l, 0);
            const float* rowp = img + ih * W;
            const float4 f4 = *(const float4*)(rowp + cbase);
            const float lf = rowp[max(cbase - 1, 0)];
            const bool rok = (l > 0) || topok;   // folds for l>0
            p[l][0] = (rok && pwok) ? lf : 0.0f;
            p[l][1] = rok ? f4.x : 0.0f;
            p[l][2] = rok ? f4.y : 0.0f;
            p[l][3] = rok ? f4.z : 0.0f;
            p[l][4] = rok ? f4.w : 0.0f;
        }
#pragma unroll
        for (int j = 0; j < 8; ++j) {
            const float* wc = w1 + ((c0 + j) * CIN + ci) * 9;  // uniform
#pragma unroll
            for (int kh = 0; kh < 3; ++kh) {
#pragma unroll
                for (int kw = 0; kw < 3; ++kw) {
                    const float wv = wc[kh * 3 + kw];
                    // cell A: conv rows l = 2*dy+kh, cols s = 2*dx+kw
                    accA[j][0] += wv * p[kh][kw];
                    accA[j][1] += wv * p[kh][kw + 2];
                    accA[j][2] += wv * p[kh + 2][kw];
                    accA[j][3] += wv * p[kh + 2][kw + 2];
                    // cell B: rows l = 4 + 2*dy+kh
                    accB[j][0] += wv * p[4 + kh][kw];
                    accB[j][1] += wv * p[4 + kh][kw + 2];
                    accB[j][2] += wv * p[6 + kh][kw];
                    accB[j][3] += wv * p[6 + kh][kw + 2];
                }
            }
        }
    }

#pragma unroll
    for (int j = 0; j < 8; ++j) {
        const int o = (n * C1 + c0 + j) * (HP * WP) + (2 * phh) * WP + pw;
        const float a0 = accA[j][0], a1 = accA[j][1], a2 = accA[j][2], a3 = accA[j][3];
        const float b0 = accB[j][0], b1v = accB[j][1], b2v = accB[j][2], b3 = accB[j][3];
        mm[o] = make_float2(fmaxf(fmaxf(a0, a1), fmaxf(a2, a3)),
                            fminf(fminf(a0, a1), fminf(a2, a3)));
        mm[o + WP] = make_float2(fmaxf(fmaxf(b0, b1v), fmaxf(b2v, b3)),
                                 fminf(fminf(b0, b1v), fminf(b2v, b3)));
        float s = a0 + a1 + a2 + a3 + b0 + b1v + b2v + b3;
        float q = a0 * a0 + a1 * a1 + a2 * a2 + a3 * a3
                + b0 * b0 + b1v * b1v + b2v * b2v + b3 * b3;
#pragma unroll
        for (int off = 32; off > 0; off >>= 1) {
            s += __shfl_xor(s, off);
            q += __shfl_xor(q, off);
        }
        if ((tid & 63) == 0) { red[tid >> 6][j] = s; redq[tid >> 6][j] = q; }
    }
    __syncthreads();
    if (tid < 8) {
        atomicAdd(&s_sum[c0 + tid],
                  red[0][tid] + red[1][tid] + red[2][tid] + red[3][tid]);
    } else if (tid < 16) {
        const int j = tid - 8;
        atomicAdd(&s_sq[c0 + j],
                  redq[0][j] + redq[1][j] + redq[2][j] + redq[3][j]);
    }
}

__global__ void finalize_bn_k(const float* __restrict__ s_sum,
                              const float* __restrict__ s_sq,
                              const float* __restrict__ g,
                              const float* __restrict__ beta,
                              float* __restrict__ sc, int C, float invcount)
{
    int c = threadIdx.x;
    if (c < C) {
        float mean = s_sum[c] * invcount;
        float var  = s_sq[c] * invcount - mean * mean;
        float scale = g[c] * rsqrtf(var + 1e-5f);
        sc[c]     = scale;
        sc[C + c] = beta[c] - mean * scale;
    }
}

// ---------------------------------------------------------------------------
// conv2 (s2,p1) + stats, reading mm directly (BN1+ReLU+pool-select in regs):
//   h1 = relu(max(s*mx+t, s*mn+t))
// Thread = 2 vertically-adjacent outputs (oh = 2*ohh, 2*ohh+1) x 8 chans.
// mm rows 4*ohh-1 .. 4*ohh+3 (5 rows; A uses l=0..2, B uses l=2..4).
// Per row: float4 @ pooled col 2*ow (2 pairs, 16B-aligned) + float2 at
// 2*ow-1 (clamped + masked). Grid (196, 4): 196*256 = 128*14*28 exactly.
// ---------------------------------------------------------------------------
__global__ __launch_bounds__(256) void conv2_k(
    const float2* __restrict__ mm, const float* __restrict__ sc1,
    const float* __restrict__ w2, const float* __restrict__ b2,
    float* __restrict__ y2,
    float* __restrict__ s_sum, float* __restrict__ s_sq)
{
    __shared__ float red[4][8], redq[4][8];
    const int tid = threadIdx.x;
    const int t = blockIdx.x * 256 + tid;   // 0..50175
    const int c0 = blockIdx.y * 8;
    const int n = t / 392;
    const int r = t % 392;
    const int ohh = r / 28;                 // 0..13
    const int ow  = r % 28;
    const int rbase = 4 * ohh - 1;
    const bool topok = ohh > 0;
    const bool owok  = ow > 0;

    float accA[8], accB[8];
#pragma unroll
    for (int c = 0; c < 8; ++c) { accA[c] = b2[c0 + c]; accB[c] = b2[c0 + c]; }

#pragma unroll 4
    for (int ci = 0; ci < C1; ++ci) {
        const float2* pl = mm + (n * C1 + ci) * (HP * WP);
        const float s1 = sc1[ci], t1 = sc1[C1 + ci];
        float v[5][3];
#pragma unroll
        for (int l = 0; l < 5; ++l) {
            const int ih = max(rbase + l, 0);
            const float2* rowp = pl + ih * WP;
            const float4 f4 = *(const float4*)(rowp + 2 * ow);   // 2 pairs
            const float2 lp = rowp[max(2 * ow - 1, 0)];
            const bool rok = (l > 0) || topok;   // folds for l>0
            const float h0 = fmaxf(0.0f, fmaxf(s1 * lp.x + t1, s1 * lp.y + t1));
            const float h1 = fmaxf(0.0f, fmaxf(s1 * f4.x + t1, s1 * f4.y + t1));
            const float h2 = fmaxf(0.0f, fmaxf(s1 * f4.z + t1, s1 * f4.w + t1));
            v[l][0] = (rok && owok) ? h0 : 0.0f;
            v[l][1] = rok ? h1 : 0.0f;
            v[l][2] = rok ? h2 : 0.0f;
        }
#pragma unroll
        for (int c = 0; c < 8; ++c) {
            const float* wc = w2 + ((c0 + c) * C1 + ci) * 9;   // uniform
            float a = accA[c];
            a += wc[0] * v[0][0]; a += wc[1] * v[0][1]; a += wc[2] * v[0][2];
            a += wc[3] * v[1][0]; a += wc[4] * v[1][1]; a += wc[5] * v[1][2];
            a += wc[6] * v[2][0]; a += wc[7] * v[2][1]; a += wc[8] * v[2][2];
            accA[c] = a;
            float b = accB[c];
            b += wc[0] * v[2][0]; b += wc[1] * v[2][1]; b += wc[2] * v[2][2];
            b += wc[3] * v[3][0]; b += wc[4] * v[3][1]; b += wc[5] * v[3][2];
            b += wc[6] * v[4][0]; b += wc[7] * v[4][1]; b += wc[8] * v[4][2];
            accB[c] = b;
        }
    }

#pragma unroll
    for (int c = 0; c < 8; ++c) {
        const int o = (n * C2 + c0 + c) * (H2 * W2) + (2 * ohh) * W2 + ow;
        y2[o] = accA[c];
        y2[o + W2] = accB[c];
        float s = accA[c] + accB[c];
        float q = accA[c] * accA[c] + accB[c] * accB[c];
#pragma unroll
        for (int off = 32; off > 0; off >>= 1) {
            s += __shfl_xor(s, off);
            q += __shfl_xor(q, off);
        }
        if ((tid & 63) == 0) { red[tid >> 6][c] = s; redq[tid >> 6][c] = q; }
    }
    __syncthreads();
    if (tid < 8) {
        atomicAdd(&s_sum[c0 + tid],
                  red[0][tid] + red[1][tid] + red[2][tid] + red[3][tid]);
    } else if (tid < 16) {
        const int c = tid - 8;
        atomicAdd(&s_sq[c0 + c],
                  redq[0][c] + redq[1][c] + redq[2][c] + redq[3][c]);
    }
}

// ---------------------------------------------------------------------------
// head: one wave per (n,c): BN2+relu+avg over 784, dot with fcw, atomic
// into per-image logit.
// ---------------------------------------------------------------------------
__global__ __launch_bounds__(64) void head_k(
    const float* __restrict__ y2, const float* __restrict__ sc2,
    const float* __restrict__ fcw, float* __restrict__ logit)
{
    const int b = blockIdx.x;
    const int n = b >> 5, c = b & 31;
    const int lane = threadIdx.x;
    const float s = sc2[c], t = sc2[C2 + c];
    const float* yp = y2 + (size_t)b * (H2 * W2);
    float acc = 0.0f;
    for (int p = lane; p < H2 * W2; p += 64)
        acc += fmaxf(0.0f, s * yp[p] + t);
#pragma unroll
    for (int off = 32; off > 0; off >>= 1) acc += __shfl_xor(acc, off);
    if (lane == 0)
        atomicAdd(&logit[n], acc * (1.0f / (H2 * W2)) * fcw[c]);
}

__global__ void cos_k(const float* __restrict__ logit,
                      const float* __restrict__ fcb, float* __restrict__ out)
{
    const int n = threadIdx.x;   // 128
    const float pc = cosf(logit[n] + fcb[0]);
    out[2 * n]     = pc;
    out[2 * n + 1] = 1.0f - pc;
}

extern "C" void kernel_launch(void* const* d_in, const int* in_sizes, int n_in,
                              void* d_out, int out_size, void* d_ws, size_t ws_size,
                              hipStream_t stream) {
    const float* x   = (const float*)d_in[0];
    const float* w1  = (const float*)d_in[1];
    const float* b1  = (const float*)d_in[2];
    const float* g1  = (const float*)d_in[3];
    const float* be1 = (const float*)d_in[4];
    const float* w2  = (const float*)d_in[5];
    const float* b2  = (const float*)d_in[6];
    const float* g2  = (const float*)d_in[7];
    const float* be2 = (const float*)d_in[8];
    const float* fcw = (const float*)d_in[9];
    const float* fcb = (const float*)d_in[10];
    float* out = (float*)d_out;

    float* ws = (float*)d_ws;
    float2* mm = (float2*)ws;                              // 6,422,528 float2
    float* y2 = ws + (size_t)2 * BATCH * C1 * HP * WP;     // 3,211,264 floats
    float* stats = y2 + (size_t)BATCH * C2 * H2 * W2;
    float* s1sum = stats;          // 16
    float* s1sq  = stats + 16;     // 16
    float* s2sum = stats + 32;     // 32
    float* s2sq  = stats + 64;     // 32
    float* logit = stats + 96;     // 128
    float* sc1   = stats + 224;    // 32
    float* sc2   = stats + 256;    // 64
    // ws use ~64.3 MB (proven safe in R2)

    hipMemsetAsync(stats, 0, 224 * sizeof(float), stream);

    conv1_fused_k<<<dim3(784, 2), 256, 0, stream>>>(x, w1, b1, mm, s1sum, s1sq);
    finalize_bn_k<<<1, 64, 0, stream>>>(s1sum, s1sq, g1, be1, sc1, C1,
                                        1.0f / (float)(BATCH * 112 * 112));
    conv2_k<<<dim3(196, 4), 256, 0, stream>>>(mm, sc1, w2, b2, y2, s2sum, s2sq);
    finalize_bn_k<<<1, 64, 0, stream>>>(s2sum, s2sq, g2, be2, sc2, C2,
                                        1.0f / (float)(BATCH * H2 * W2));
    head_k<<<BATCH * C2, 64, 0, stream>>>(y2, sc2, fcw, logit);
    cos_k<<<1, BATCH, 0, stream>>>(logit, fcb, out);
}

// Round 6
// 216.920 us; speedup vs baseline: 2.4371x; 1.1083x over previous
//
#include <hip/hip_runtime.h>
#include <math.h>

#define BATCH 128
#define CIN 3
#define H 224
#define W 224
#define C1 16
#define HP 56
#define WP 56
#define C2 32
#define H2 28
#define W2 28

// ---------------------------------------------------------------------------
// conv1 (s2,p1) + stats + 2x2 pool(max,min), SINGLE PASS (unchanged from R5).
// Thread = 2 vertically-adjacent pooled cells x 8 channels. Grid (784, 2).
// ---------------------------------------------------------------------------
__global__ __launch_bounds__(256) void conv1_fused_k(
    const float* __restrict__ x, const float* __restrict__ w1,
    const float* __restrict__ b1, float2* __restrict__ mm,
    float* __restrict__ s_sum, float* __restrict__ s_sq)
{
    __shared__ float red[4][8], redq[4][8];
    const int tid = threadIdx.x;
    const int t = blockIdx.x * 256 + tid;   // 0..200703
    const int c0 = blockIdx.y * 8;
    const int n = t / 1568;
    const int r = t % 1568;
    const int phh = r / 56;                 // 0..27
    const int pw  = r % 56;
    const int rbase = 8 * phh - 1;
    const int cbase = 4 * pw;
    const bool topok = phh > 0;
    const bool pwok  = pw > 0;

    float accA[8][4], accB[8][4];
#pragma unroll
    for (int j = 0; j < 8; ++j) {
        const float bb = b1[c0 + j];
#pragma unroll
        for (int q = 0; q < 4; ++q) { accA[j][q] = bb; accB[j][q] = bb; }
    }

#pragma unroll
    for (int ci = 0; ci < CIN; ++ci) {
        const float* img = x + (n * CIN + ci) * (H * W);
        float p[9][5];
#pragma unroll
        for (int l = 0; l < 9; ++l) {
            const int ih = max(rbase + l, 0);
            const float* rowp = img + ih * W;
            const float4 f4 = *(const float4*)(rowp + cbase);
            const float lf = rowp[max(cbase - 1, 0)];
            const bool rok = (l > 0) || topok;   // folds for l>0
            p[l][0] = (rok && pwok) ? lf : 0.0f;
            p[l][1] = rok ? f4.x : 0.0f;
            p[l][2] = rok ? f4.y : 0.0f;
            p[l][3] = rok ? f4.z : 0.0f;
            p[l][4] = rok ? f4.w : 0.0f;
        }
#pragma unroll
        for (int j = 0; j < 8; ++j) {
            const float* wc = w1 + ((c0 + j) * CIN + ci) * 9;  // uniform
#pragma unroll
            for (int kh = 0; kh < 3; ++kh) {
#pragma unroll
                for (int kw = 0; kw < 3; ++kw) {
                    const float wv = wc[kh * 3 + kw];
                    accA[j][0] += wv * p[kh][kw];
                    accA[j][1] += wv * p[kh][kw + 2];
                    accA[j][2] += wv * p[kh + 2][kw];
                    accA[j][3] += wv * p[kh + 2][kw + 2];
                    accB[j][0] += wv * p[4 + kh][kw];
                    accB[j][1] += wv * p[4 + kh][kw + 2];
                    accB[j][2] += wv * p[6 + kh][kw];
                    accB[j][3] += wv * p[6 + kh][kw + 2];
                }
            }
        }
    }

#pragma unroll
    for (int j = 0; j < 8; ++j) {
        const int o = (n * C1 + c0 + j) * (HP * WP) + (2 * phh) * WP + pw;
        const float a0 = accA[j][0], a1 = accA[j][1], a2 = accA[j][2], a3 = accA[j][3];
        const float b0 = accB[j][0], b1v = accB[j][1], b2v = accB[j][2], b3 = accB[j][3];
        mm[o] = make_float2(fmaxf(fmaxf(a0, a1), fmaxf(a2, a3)),
                            fminf(fminf(a0, a1), fminf(a2, a3)));
        mm[o + WP] = make_float2(fmaxf(fmaxf(b0, b1v), fmaxf(b2v, b3)),
                                 fminf(fminf(b0, b1v), fminf(b2v, b3)));
        float s = a0 + a1 + a2 + a3 + b0 + b1v + b2v + b3;
        float q = a0 * a0 + a1 * a1 + a2 * a2 + a3 * a3
                + b0 * b0 + b1v * b1v + b2v * b2v + b3 * b3;
#pragma unroll
        for (int off = 32; off > 0; off >>= 1) {
            s += __shfl_xor(s, off);
            q += __shfl_xor(q, off);
        }
        if ((tid & 63) == 0) { red[tid >> 6][j] = s; redq[tid >> 6][j] = q; }
    }
    __syncthreads();
    if (tid < 8) {
        atomicAdd(&s_sum[c0 + tid],
                  red[0][tid] + red[1][tid] + red[2][tid] + red[3][tid]);
    } else if (tid < 16) {
        const int j = tid - 8;
        atomicAdd(&s_sq[c0 + j],
                  redq[0][j] + redq[1][j] + redq[2][j] + redq[3][j]);
    }
}

// ---------------------------------------------------------------------------
// conv2 (s2,p1) + stats; BN1 finalize folded in (uniform scalar math per ci,
// loop body has no stores so the compiler can hoist/CSE the s_loads).
// Thread = ONE output position x 8 channels. Grid (392, 4) = 1568 blocks
// = 24.5 waves/CU (2x R5) — restores latency hiding.
//   h1 = relu(max(s*mx+t, s*mn+t)) from interleaved (mx,mn) pairs.
// ---------------------------------------------------------------------------
__global__ __launch_bounds__(256) void conv2_k(
    const float2* __restrict__ mm,
    const float* __restrict__ s1sum, const float* __restrict__ s1sq,
    const float* __restrict__ g1, const float* __restrict__ be1,
    const float* __restrict__ w2, const float* __restrict__ b2,
    float* __restrict__ y2,
    float* __restrict__ s_sum, float* __restrict__ s_sq)
{
    __shared__ float red[4][8], redq[4][8];
    const int tid = threadIdx.x;
    const int t = blockIdx.x * 256 + tid;   // 0..100351
    const int c0 = blockIdx.y * 8;
    const int n = t / 784;
    const int p = t % 784;
    const int oh = p / W2, ow = p % W2;
    const bool topok = oh > 0;
    const bool owok  = ow > 0;
    const float inv1 = 1.0f / (float)(BATCH * 112 * 112);

    float acc[8];
#pragma unroll
    for (int c = 0; c < 8; ++c) acc[c] = b2[c0 + c];

#pragma unroll 2
    for (int ci = 0; ci < C1; ++ci) {
        // BN1 params (uniform; scalar pipe)
        const float mean = s1sum[ci] * inv1;
        const float var  = s1sq[ci] * inv1 - mean * mean;
        const float s1 = g1[ci] * rsqrtf(var + 1e-5f);
        const float t1 = be1[ci] - mean * s1;

        const float2* pl = mm + (n * C1 + ci) * (HP * WP);
        float v[3][3];
#pragma unroll
        for (int kh = 0; kh < 3; ++kh) {
            const int ih = max(2 * oh - 1 + kh, 0);
            const float2* rowp = pl + ih * WP;
            const float4 f4 = *(const float4*)(rowp + 2 * ow);   // pairs @2ow,2ow+1
            const float2 lp = rowp[max(2 * ow - 1, 0)];
            const bool rok = (kh > 0) || topok;   // folds for kh>0
            const float h0 = fmaxf(0.0f, fmaxf(s1 * lp.x + t1, s1 * lp.y + t1));
            const float h1 = fmaxf(0.0f, fmaxf(s1 * f4.x + t1, s1 * f4.y + t1));
            const float h2 = fmaxf(0.0f, fmaxf(s1 * f4.z + t1, s1 * f4.w + t1));
            v[kh][0] = (rok && owok) ? h0 : 0.0f;
            v[kh][1] = rok ? h1 : 0.0f;
            v[kh][2] = rok ? h2 : 0.0f;
        }
#pragma unroll
        for (int c = 0; c < 8; ++c) {
            const float* wc = w2 + ((c0 + c) * C1 + ci) * 9;   // uniform
            float a = acc[c];
            a += wc[0] * v[0][0]; a += wc[1] * v[0][1]; a += wc[2] * v[0][2];
            a += wc[3] * v[1][0]; a += wc[4] * v[1][1]; a += wc[5] * v[1][2];
            a += wc[6] * v[2][0]; a += wc[7] * v[2][1]; a += wc[8] * v[2][2];
            acc[c] = a;
        }
    }

#pragma unroll
    for (int c = 0; c < 8; ++c) {
        const float a = acc[c];
        y2[(n * C2 + c0 + c) * (H2 * W2) + p] = a;
        float s = a, q = a * a;
#pragma unroll
        for (int off = 32; off > 0; off >>= 1) {
            s += __shfl_xor(s, off);
            q += __shfl_xor(q, off);
        }
        if ((tid & 63) == 0) { red[tid >> 6][c] = s; redq[tid >> 6][c] = q; }
    }
    __syncthreads();
    if (tid < 8) {
        atomicAdd(&s_sum[c0 + tid],
                  red[0][tid] + red[1][tid] + red[2][tid] + red[3][tid]);
    } else if (tid < 16) {
        const int c = tid - 8;
        atomicAdd(&s_sq[c0 + c],
                  redq[0][c] + redq[1][c] + redq[2][c] + redq[3][c]);
    }
}

// ---------------------------------------------------------------------------
// head: one wave per (n,c); BN2 finalize folded in. BN2+relu+avg over 784,
// dot with fcw, atomic into per-image logit.
// ---------------------------------------------------------------------------
__global__ __launch_bounds__(64) void head_k(
    const float* __restrict__ y2,
    const float* __restrict__ s2sum, const float* __restrict__ s2sq,
    const float* __restrict__ g2, const float* __restrict__ be2,
    const float* __restrict__ fcw, float* __restrict__ logit)
{
    const int b = blockIdx.x;
    const int n = b >> 5, c = b & 31;
    const int lane = threadIdx.x;
    const float inv2 = 1.0f / (float)(BATCH * H2 * W2);
    const float mean = s2sum[c] * inv2;
    const float var  = s2sq[c] * inv2 - mean * mean;
    const float s = g2[c] * rsqrtf(var + 1e-5f);
    const float t = be2[c] - mean * s;
    const float* yp = y2 + (size_t)b * (H2 * W2);
    float acc = 0.0f;
    for (int p = lane; p < H2 * W2; p += 64)
        acc += fmaxf(0.0f, s * yp[p] + t);
#pragma unroll
    for (int off = 32; off > 0; off >>= 1) acc += __shfl_xor(acc, off);
    if (lane == 0)
        atomicAdd(&logit[n], acc * (1.0f / (H2 * W2)) * fcw[c]);
}

__global__ void cos_k(const float* __restrict__ logit,
                      const float* __restrict__ fcb, float* __restrict__ out)
{
    const int n = threadIdx.x;   // 128
    const float pc = cosf(logit[n] + fcb[0]);
    out[2 * n]     = pc;
    out[2 * n + 1] = 1.0f - pc;
}

extern "C" void kernel_launch(void* const* d_in, const int* in_sizes, int n_in,
                              void* d_out, int out_size, void* d_ws, size_t ws_size,
                              hipStream_t stream) {
    const float* x   = (const float*)d_in[0];
    const float* w1  = (const float*)d_in[1];
    const float* b1  = (const float*)d_in[2];
    const float* g1  = (const float*)d_in[3];
    const float* be1 = (const float*)d_in[4];
    const float* w2  = (const float*)d_in[5];
    const float* b2  = (const float*)d_in[6];
    const float* g2  = (const float*)d_in[7];
    const float* be2 = (const float*)d_in[8];
    const float* fcw = (const float*)d_in[9];
    const float* fcb = (const float*)d_in[10];
    float* out = (float*)d_out;

    float* ws = (float*)d_ws;
    float2* mm = (float2*)ws;                              // 6,422,528 float2
    float* y2 = ws + (size_t)2 * BATCH * C1 * HP * WP;     // 3,211,264 floats
    float* stats = y2 + (size_t)BATCH * C2 * H2 * W2;
    float* s1sum = stats;          // 16
    float* s1sq  = stats + 16;     // 16
    float* s2sum = stats + 32;     // 32
    float* s2sq  = stats + 64;     // 32
    float* logit = stats + 96;     // 128
    // ws use ~64.3 MB (proven safe)

    hipMemsetAsync(stats, 0, 224 * sizeof(float), stream);

    conv1_fused_k<<<dim3(784, 2), 256, 0, stream>>>(x, w1, b1, mm, s1sum, s1sq);
    conv2_k<<<dim3(392, 4), 256, 0, stream>>>(mm, s1sum, s1sq, g1, be1,
                                              w2, b2, y2, s2sum, s2sq);
    head_k<<<BATCH * C2, 64, 0, stream>>>(y2, s2sum, s2sq, g2, be2, fcw, logit);
    cos_k<<<1, BATCH, 0, stream>>>(logit, fcb, out);
}

// Round 8
// 214.952 us; speedup vs baseline: 2.4594x; 1.0092x over previous
//
#include <hip/hip_runtime.h>
#include <math.h>

#define BATCH 128
#define CIN 3
#define H 224
#define W 224
#define C1 16
#define HP 56
#define WP 56
#define C2 32
#define H2 28
#define W2 28

// ---------------------------------------------------------------------------
// conv1 (s2,p1) + stats + 2x2 pool(max,min), SINGLE PASS (R6-proven).
// Thread = 2 vertically-adjacent pooled cells x 8 channels. Grid (784, 2).
// ---------------------------------------------------------------------------
__global__ __launch_bounds__(256) void conv1_fused_k(
    const float* __restrict__ x, const float* __restrict__ w1,
    const float* __restrict__ b1, float2* __restrict__ mm,
    float* __restrict__ s_sum, float* __restrict__ s_sq)
{
    __shared__ float red[4][8], redq[4][8];
    const int tid = threadIdx.x;
    const int t = blockIdx.x * 256 + tid;   // 0..200703
    const int c0 = blockIdx.y * 8;
    const int n = t / 1568;
    const int r = t % 1568;
    const int phh = r / 56;                 // 0..27
    const int pw  = r % 56;
    const int rbase = 8 * phh - 1;
    const int cbase = 4 * pw;
    const bool topok = phh > 0;
    const bool pwok  = pw > 0;

    float accA[8][4], accB[8][4];
#pragma unroll
    for (int j = 0; j < 8; ++j) {
        const float bb = b1[c0 + j];
#pragma unroll
        for (int q = 0; q < 4; ++q) { accA[j][q] = bb; accB[j][q] = bb; }
    }

#pragma unroll
    for (int ci = 0; ci < CIN; ++ci) {
        const float* img = x + (n * CIN + ci) * (H * W);
        float p[9][5];
#pragma unroll
        for (int l = 0; l < 9; ++l) {
            const int ih = max(rbase + l, 0);
            const float* rowp = img + ih * W;
            const float4 f4 = *(const float4*)(rowp + cbase);
            const float lf = rowp[max(cbase - 1, 0)];
            const bool rok = (l > 0) || topok;   // folds for l>0
            p[l][0] = (rok && pwok) ? lf : 0.0f;
            p[l][1] = rok ? f4.x : 0.0f;
            p[l][2] = rok ? f4.y : 0.0f;
            p[l][3] = rok ? f4.z : 0.0f;
            p[l][4] = rok ? f4.w : 0.0f;
        }
#pragma unroll
        for (int j = 0; j < 8; ++j) {
            const float* wc = w1 + ((c0 + j) * CIN + ci) * 9;  // uniform
#pragma unroll
            for (int kh = 0; kh < 3; ++kh) {
#pragma unroll
                for (int kw = 0; kw < 3; ++kw) {
                    const float wv = wc[kh * 3 + kw];
                    accA[j][0] += wv * p[kh][kw];
                    accA[j][1] += wv * p[kh][kw + 2];
                    accA[j][2] += wv * p[kh + 2][kw];
                    accA[j][3] += wv * p[kh + 2][kw + 2];
                    accB[j][0] += wv * p[4 + kh][kw];
                    accB[j][1] += wv * p[4 + kh][kw + 2];
                    accB[j][2] += wv * p[6 + kh][kw];
                    accB[j][3] += wv * p[6 + kh][kw + 2];
                }
            }
        }
    }

#pragma unroll
    for (int j = 0; j < 8; ++j) {
        const int o = (n * C1 + c0 + j) * (HP * WP) + (2 * phh) * WP + pw;
        const float a0 = accA[j][0], a1 = accA[j][1], a2 = accA[j][2], a3 = accA[j][3];
        const float b0 = accB[j][0], b1v = accB[j][1], b2v = accB[j][2], b3 = accB[j][3];
        mm[o] = make_float2(fmaxf(fmaxf(a0, a1), fmaxf(a2, a3)),
                            fminf(fminf(a0, a1), fminf(a2, a3)));
        mm[o + WP] = make_float2(fmaxf(fmaxf(b0, b1v), fmaxf(b2v, b3)),
                                 fminf(fminf(b0, b1v), fminf(b2v, b3)));
        float s = a0 + a1 + a2 + a3 + b0 + b1v + b2v + b3;
        float q = a0 * a0 + a1 * a1 + a2 * a2 + a3 * a3
                + b0 * b0 + b1v * b1v + b2v * b2v + b3 * b3;
#pragma unroll
        for (int off = 32; off > 0; off >>= 1) {
            s += __shfl_xor(s, off);
            q += __shfl_xor(q, off);
        }
        if ((tid & 63) == 0) { red[tid >> 6][j] = s; redq[tid >> 6][j] = q; }
    }
    __syncthreads();
    if (tid < 8) {
        atomicAdd(&s_sum[c0 + tid],
                  red[0][tid] + red[1][tid] + red[2][tid] + red[3][tid]);
    } else if (tid < 16) {
        const int j = tid - 8;
        atomicAdd(&s_sq[c0 + j],
                  redq[0][j] + redq[1][j] + redq[2][j] + redq[3][j]);
    }
}

// ---------------------------------------------------------------------------
// conv2 (s2,p1) + stats; BN1 finalize folded in (R6-proven).
// Thread = ONE output position x 8 channels. Grid (392, 4).
// ---------------------------------------------------------------------------
__global__ __launch_bounds__(256) void conv2_k(
    const float2* __restrict__ mm,
    const float* __restrict__ s1sum, const float* __restrict__ s1sq,
    const float* __restrict__ g1, const float* __restrict__ be1,
    const float* __restrict__ w2, const float* __restrict__ b2,
    float* __restrict__ y2,
    float* __restrict__ s_sum, float* __restrict__ s_sq)
{
    __shared__ float red[4][8], redq[4][8];
    const int tid = threadIdx.x;
    const int t = blockIdx.x * 256 + tid;   // 0..100351
    const int c0 = blockIdx.y * 8;
    const int n = t / 784;
    const int p = t % 784;
    const int oh = p / W2, ow = p % W2;
    const bool topok = oh > 0;
    const bool owok  = ow > 0;
    const float inv1 = 1.0f / (float)(BATCH * 112 * 112);

    float acc[8];
#pragma unroll
    for (int c = 0; c < 8; ++c) acc[c] = b2[c0 + c];

#pragma unroll 2
    for (int ci = 0; ci < C1; ++ci) {
        const float mean = s1sum[ci] * inv1;
        const float var  = s1sq[ci] * inv1 - mean * mean;
        const float s1 = g1[ci] * rsqrtf(var + 1e-5f);
        const float t1 = be1[ci] - mean * s1;

        const float2* pl = mm + (n * C1 + ci) * (HP * WP);
        float v[3][3];
#pragma unroll
        for (int kh = 0; kh < 3; ++kh) {
            const int ih = max(2 * oh - 1 + kh, 0);
            const float2* rowp = pl + ih * WP;
            const float4 f4 = *(const float4*)(rowp + 2 * ow);
            const float2 lp = rowp[max(2 * ow - 1, 0)];
            const bool rok = (kh > 0) || topok;   // folds for kh>0
            const float h0 = fmaxf(0.0f, fmaxf(s1 * lp.x + t1, s1 * lp.y + t1));
            const float h1 = fmaxf(0.0f, fmaxf(s1 * f4.x + t1, s1 * f4.y + t1));
            const float h2 = fmaxf(0.0f, fmaxf(s1 * f4.z + t1, s1 * f4.w + t1));
            v[kh][0] = (rok && owok) ? h0 : 0.0f;
            v[kh][1] = rok ? h1 : 0.0f;
            v[kh][2] = rok ? h2 : 0.0f;
        }
#pragma unroll
        for (int c = 0; c < 8; ++c) {
            const float* wc = w2 + ((c0 + c) * C1 + ci) * 9;   // uniform
            float a = acc[c];
            a += wc[0] * v[0][0]; a += wc[1] * v[0][1]; a += wc[2] * v[0][2];
            a += wc[3] * v[1][0]; a += wc[4] * v[1][1]; a += wc[5] * v[1][2];
            a += wc[6] * v[2][0]; a += wc[7] * v[2][1]; a += wc[8] * v[2][2];
            acc[c] = a;
        }
    }

#pragma unroll
    for (int c = 0; c < 8; ++c) {
        const float a = acc[c];
        y2[(n * C2 + c0 + c) * (H2 * W2) + p] = a;
        float s = a, q = a * a;
#pragma unroll
        for (int off = 32; off > 0; off >>= 1) {
            s += __shfl_xor(s, off);
            q += __shfl_xor(q, off);
        }
        if ((tid & 63) == 0) { red[tid >> 6][c] = s; redq[tid >> 6][c] = q; }
    }
    __syncthreads();
    if (tid < 8) {
        atomicAdd(&s_sum[c0 + tid],
                  red[0][tid] + red[1][tid] + red[2][tid] + red[3][tid]);
    } else if (tid < 16) {
        const int c = tid - 8;
        atomicAdd(&s_sq[c0 + c],
                  redq[0][c] + redq[1][c] + redq[2][c] + redq[3][c]);
    }
}

// ---------------------------------------------------------------------------
// head fused: BN2 finalize + ReLU + avgpool + FC + cos, one block per image.
// Wave w handles channels 8w..8w+7; float4 loads (784 = 196 quads, 16B ok).
// No atomics, no logit buffer, replaces head_k + cos_k.
// ---------------------------------------------------------------------------
__global__ __launch_bounds__(256) void head_fused_k(
    const float* __restrict__ y2,
    const float* __restrict__ s2sum, const float* __restrict__ s2sq,
    const float* __restrict__ g2, const float* __restrict__ be2,
    const float* __restrict__ fcw, const float* __restrict__ fcb,
    float* __restrict__ out)
{
    __shared__ float feat[C2];
    const int n = blockIdx.x;
    const int tid = threadIdx.x;
    const int wave = tid >> 6, lane = tid & 63;
    const float inv2 = 1.0f / (float)(BATCH * H2 * W2);
#pragma unroll
    for (int k = 0; k < 8; ++k) {
        const int c = wave * 8 + k;
        const float mean = s2sum[c] * inv2;
        const float var  = s2sq[c] * inv2 - mean * mean;
        const float s = g2[c] * rsqrtf(var + 1e-5f);
        const float t = be2[c] - mean * s;
        const float4* yp = (const float4*)(y2 + (n * C2 + c) * (H2 * W2));
        float a = 0.0f;
        for (int i = lane; i < 196; i += 64) {       // 196 quads = 784
            const float4 v = yp[i];
            a += fmaxf(0.0f, s * v.x + t) + fmaxf(0.0f, s * v.y + t)
               + fmaxf(0.0f, s * v.z + t) + fmaxf(0.0f, s * v.w + t);
        }
#pragma unroll
        for (int off = 32; off > 0; off >>= 1) a += __shfl_xor(a, off);
        if (lane == 0) feat[c] = a * (1.0f / (H2 * W2));
    }
    __syncthreads();
    if (tid == 0) {
        float logit = fcb[0];
#pragma unroll
        for (int c = 0; c < C2; ++c) logit += feat[c] * fcw[c];
        const float pc = cosf(logit);
        out[2 * n]     = pc;
        out[2 * n + 1] = 1.0f - pc;
    }
}

extern "C" void kernel_launch(void* const* d_in, const int* in_sizes, int n_in,
                              void* d_out, int out_size, void* d_ws, size_t ws_size,
                              hipStream_t stream) {
    const float* x   = (const float*)d_in[0];
    const float* w1  = (const float*)d_in[1];
    const float* b1  = (const float*)d_in[2];
    const float* g1  = (const float*)d_in[3];
    const float* be1 = (const float*)d_in[4];
    const float* w2  = (const float*)d_in[5];
    const float* b2  = (const float*)d_in[6];
    const float* g2  = (const float*)d_in[7];
    const float* be2 = (const float*)d_in[8];
    const float* fcw = (const float*)d_in[9];
    const float* fcb = (const float*)d_in[10];
    float* out = (float*)d_out;

    float* ws = (float*)d_ws;
    float2* mm = (float2*)ws;                              // 6,422,528 float2
    float* y2 = ws + (size_t)2 * BATCH * C1 * HP * WP;     // 3,211,264 floats
    float* stats = y2 + (size_t)BATCH * C2 * H2 * W2;
    float* s1sum = stats;          // 16
    float* s1sq  = stats + 16;     // 16
    float* s2sum = stats + 32;     // 32
    float* s2sq  = stats + 64;     // 32
    // ws use ~64.3 MB (proven safe)

    hipMemsetAsync(stats, 0, 96 * sizeof(float), stream);

    conv1_fused_k<<<dim3(784, 2), 256, 0, stream>>>(x, w1, b1, mm, s1sum, s1sq);
    conv2_k<<<dim3(392, 4), 256, 0, stream>>>(mm, s1sum, s1sq, g1, be1,
                                              w2, b2, y2, s2sum, s2sq);
    head_fused_k<<<BATCH, 256, 0, stream>>>(y2, s2sum, s2sq, g2, be2,
                                            fcw, fcb, out);
}